// Round 5
// baseline (347.955 us; speedup 1.0000x reference)
//
#include <hip/hip_runtime.h>
#include <math.h>

typedef _Float16 f16;
typedef f16 f16x8 __attribute__((ext_vector_type(8)));
typedef f16 f16x4 __attribute__((ext_vector_type(4)));
typedef float f32x4 __attribute__((ext_vector_type(4)));

#define H_   8
#define E_   512
#define DK   64
#define BB   16
#define T1C  512
#define T2C  512
#define NPOS 1023

// ---------------- fused fp16-MFMA projection GEMM, fp32 inputs ----------------
// C = A(M,512) @ W(512,512)^T + bias (+bias2). A fp32 (or f16 when a16=1), W fp32.
// Double-buffered LDS, 1 barrier/k-step, register prefetch.
// modes: 0 fp32 row-major (M,512) | 1 f16 (B,H,DK,512) | 2 f16 (B,H,512,DK) | 3 f16 (B,H,NPOS,DK)
struct PArg {
    const void* A; const float* W; const float* bias; const float* bias2;
    void* C; int Mvalid; int mode; int a16;
};
struct PArg4 { PArg g[4]; };

__device__ __forceinline__ void proj_body(const PArg g, int bx, int by) {
    __shared__ f16 Al[2][128 * 40];
    __shared__ f16 Wl[2][128 * 40];
    const int tid = threadIdx.x;
    const int lane = tid & 63, wid = tid >> 6;
    const int l15 = lane & 15, q8 = (lane >> 4) * 8;
    const int m0 = by * 128, n0 = bx * 128;
    const int wm0 = (wid & 1) * 64, wn0 = (wid >> 1) * 64;
    const int row = tid >> 1, koff = (tid & 1) * 16;
    const int arow = (m0 + row < g.Mvalid) ? (m0 + row) : (g.Mvalid - 1);

    f32x4 acc[4][4];
    #pragma unroll
    for (int a = 0; a < 4; ++a)
        #pragma unroll
        for (int b = 0; b < 4; ++b)
            acc[a][b] = (f32x4){0.f, 0.f, 0.f, 0.f};

    float4 fa[4], fw[4];
    uint4 ha[2];

    auto loadT = [&](int k0) {
        if (g.a16) {
            const f16* A16 = (const f16*)g.A;
            ha[0] = *(const uint4*)&A16[(size_t)arow * 512 + k0 + koff];
            ha[1] = *(const uint4*)&A16[(size_t)arow * 512 + k0 + koff + 8];
        } else {
            const float* A32 = (const float*)g.A;
            #pragma unroll
            for (int q = 0; q < 4; ++q)
                fa[q] = *(const float4*)&A32[(size_t)arow * 512 + k0 + koff + q * 4];
        }
        #pragma unroll
        for (int q = 0; q < 4; ++q)
            fw[q] = *(const float4*)&g.W[(size_t)(n0 + row) * 512 + k0 + koff + q * 4];
    };
    auto storeT = [&](int buf) {
        if (g.a16) {
            *(uint4*)&Al[buf][row * 40 + koff] = ha[0];
            *(uint4*)&Al[buf][row * 40 + koff + 8] = ha[1];
        } else {
            #pragma unroll
            for (int q = 0; q < 2; ++q) {
                f16x8 h;
                h[0] = (f16)fa[q*2].x; h[1] = (f16)fa[q*2].y; h[2] = (f16)fa[q*2].z; h[3] = (f16)fa[q*2].w;
                h[4] = (f16)fa[q*2+1].x; h[5] = (f16)fa[q*2+1].y; h[6] = (f16)fa[q*2+1].z; h[7] = (f16)fa[q*2+1].w;
                *(f16x8*)&Al[buf][row * 40 + koff + q * 8] = h;
            }
        }
        #pragma unroll
        for (int q = 0; q < 2; ++q) {
            f16x8 h;
            h[0] = (f16)fw[q*2].x; h[1] = (f16)fw[q*2].y; h[2] = (f16)fw[q*2].z; h[3] = (f16)fw[q*2].w;
            h[4] = (f16)fw[q*2+1].x; h[5] = (f16)fw[q*2+1].y; h[6] = (f16)fw[q*2+1].z; h[7] = (f16)fw[q*2+1].w;
            *(f16x8*)&Wl[buf][row * 40 + koff + q * 8] = h;
        }
    };

    loadT(0);
    for (int ki = 0; ki < 16; ++ki) {
        const int buf = ki & 1;
        storeT(buf);
        __syncthreads();
        if (ki < 15) loadT((ki + 1) * 32);
        f16x8 af[4], bf[4];
        #pragma unroll
        for (int t = 0; t < 4; ++t) {
            af[t] = *(const f16x8*)&Al[buf][(wm0 + t * 16 + l15) * 40 + q8];
            bf[t] = *(const f16x8*)&Wl[buf][(wn0 + t * 16 + l15) * 40 + q8];
        }
        #pragma unroll
        for (int tm = 0; tm < 4; ++tm)
            #pragma unroll
            for (int tn = 0; tn < 4; ++tn)
                acc[tm][tn] = __builtin_amdgcn_mfma_f32_16x16x32_f16(af[tm], bf[tn], acc[tm][tn], 0, 0, 0);
    }

    // C/D layout: col = lane&15, row = (lane>>4)*4 + reg
    #pragma unroll
    for (int tm = 0; tm < 4; ++tm) {
        const int mb = m0 + wm0 + tm * 16 + (lane >> 4) * 4;
        #pragma unroll
        for (int tn = 0; tn < 4; ++tn) {
            const int n = n0 + wn0 + tn * 16 + l15;
            const f32x4 a = acc[tm][tn];
            float bs = g.bias ? g.bias[n] : 0.f;
            if (g.bias2) bs += g.bias2[n];
            if (g.mode == 0) {
                float* C = (float*)g.C;
                #pragma unroll
                for (int r = 0; r < 4; ++r) C[(size_t)(mb + r) * 512 + n] = a[r] + bs;
            } else if (g.mode == 1) {
                f16* C = (f16*)g.C;
                const int b = mb >> 9, t = mb & 511;
                const int hh = n >> 6, dk = n & 63;
                f16x4 h;
                #pragma unroll
                for (int r = 0; r < 4; ++r) h[r] = (f16)(a[r] + bs);
                *(f16x4*)&C[(((size_t)b * H_ + hh) * DK + dk) * 512 + t] = h;
            } else if (g.mode == 2) {
                f16* C = (f16*)g.C;
                const int b = mb >> 9, t = mb & 511;
                const int hh = n >> 6, dk = n & 63;
                #pragma unroll
                for (int r = 0; r < 4; ++r)
                    C[(((size_t)b * H_ + hh) * 512 + t + r) * DK + dk] = (f16)(a[r] + bs);
            } else {
                f16* C = (f16*)g.C;
                const int hh = n >> 6, dk = n & 63;
                #pragma unroll
                for (int r = 0; r < 4; ++r) {
                    const int m = mb + r;
                    if (m < g.Mvalid) {
                        const int b = m / NPOS, t = m - b * NPOS;
                        C[(((size_t)b * H_ + hh) * NPOS + t) * DK + dk] = (f16)a[r];
                    }
                }
            }
        }
    }
}

// one launch: q (256 blocks) | k (256) | v (256) | pos (512)
__global__ __launch_bounds__(256) void proj_fused(PArg4 args) {
    const int blk = blockIdx.x;
    int gi, bx, by;
    if (blk < 768) { gi = blk >> 8; const int r = blk & 255; bx = r & 3; by = r >> 2; }
    else           { gi = 3;        const int r = blk - 768; bx = r & 3; by = r >> 2; }
    proj_body(args.g[gi], bx, by);
}
__global__ __launch_bounds__(256) void proj_one(PArg g) {
    proj_body(g, blockIdx.x, blockIdx.y);
}

// ---------------- MFMA flash attention with rel-shift ----------------
// Block = (64-row i-tile, h, b); 4 waves; wave w owns rows [w*16, w*16+16).
// LDS: Qa 9216 + Ka 9216 (->W) + Va 9216 + Pa 18432 (->BDW) + Ma 4096 = 50176 B -> 3 blocks/CU
__global__ __launch_bounds__(256) void attn_mfma(
    const f16* __restrict__ Qh,   // (B,H,T1,DK) = q + bq + pbu
    const f16* __restrict__ Kh,   // (B,H,T2,DK)
    const f16* __restrict__ Vt,   // (B,H,DK,T2)
    const f16* __restrict__ Ph,   // (B,H,NPOS,DK)
    const float* __restrict__ pbu, const float* __restrict__ pbv,
    const unsigned char* __restrict__ bmask,   // (B,T2)
    const unsigned char* __restrict__ cmask,   // (T1,T1)
    f16* __restrict__ CTX)        // (B,T1,E) f16
{
    __shared__ f16 Qa[64 * 72];
    __shared__ f16 Ka[64 * 72];             // K tile; reused as W[r][j]
    __shared__ f16 Va[64 * 72];             // V^T tile [d][j]
    __shared__ f16 Pa[128 * 72];            // P window [nw][d]; reused as BDW[nw][68]
    __shared__ unsigned char Ma[64 * 64];   // combined mask tile [r][c]

    const int tid = threadIdx.x;
    const int lane = tid & 63, w = tid >> 6;
    const int quad = lane >> 4, l15 = lane & 15;
    const int it = blockIdx.x, h = blockIdx.y, b = blockIdx.z;
    const int i0 = it * 64;
    const int bh = b * H_ + h;
    const int rowt = w * 16 + quad * 4;

    // stage Q tile (pbu/bq pre-folded)
    #pragma unroll
    for (int rep = 0; rep < 2; ++rep) {
        const int flat = rep * 2048 + tid * 8;
        const int r = flat >> 6, c = flat & 63;
        *(uint4*)&Qa[r * 72 + c] = *(const uint4*)&Qh[((size_t)bh * 512 + i0 + r) * 64 + c];
    }
    f16x8 dpbf[2];
    #pragma unroll
    for (int ks = 0; ks < 2; ++ks)
        #pragma unroll
        for (int j = 0; j < 8; ++j) {
            const int d = ks * 32 + quad * 8 + j;
            dpbf[ks][j] = (f16)(pbv[h * 64 + d] - pbu[h * 64 + d]);
        }

    // tile prefetch registers
    uint4 rK[2], rV[2], rP[4], rCM, rBM;
    const int mr = tid >> 2, mc = (tid & 3) * 16;
    auto load_tiles = [&](int jt) {
        const int j0 = jt * 64;
        const int nbase = j0 - i0 + 448;   // [0, 896]
        #pragma unroll
        for (int rep = 0; rep < 2; ++rep) {
            const int flat = rep * 2048 + tid * 8;
            const int r = flat >> 6, c = flat & 63;
            rK[rep] = *(const uint4*)&Kh[((size_t)bh * 512 + j0 + r) * 64 + c];
            rV[rep] = *(const uint4*)&Vt[((size_t)bh * 64 + r) * 512 + j0 + c];
        }
        #pragma unroll
        for (int rep = 0; rep < 4; ++rep) {
            const int flat = rep * 2048 + tid * 8;
            const int nw = flat >> 6, c = flat & 63;
            int n = nbase + nw; n = n > (NPOS - 1) ? (NPOS - 1) : n;  // nw=127 unused
            rP[rep] = *(const uint4*)&Ph[((size_t)bh * NPOS + n) * 64 + c];
        }
        rCM = *(const uint4*)&cmask[(size_t)(i0 + mr) * 512 + j0 + mc];
        rBM = *(const uint4*)&bmask[(size_t)b * 512 + j0 + mc];
    };
    auto store_tiles = [&]() {
        #pragma unroll
        for (int rep = 0; rep < 2; ++rep) {
            const int flat = rep * 2048 + tid * 8;
            const int r = flat >> 6, c = flat & 63;
            *(uint4*)&Ka[r * 72 + c] = rK[rep];
            *(uint4*)&Va[r * 72 + c] = rV[rep];
        }
        #pragma unroll
        for (int rep = 0; rep < 4; ++rep) {
            const int flat = rep * 2048 + tid * 8;
            const int nw = flat >> 6, c = flat & 63;
            *(uint4*)&Pa[nw * 72 + c] = rP[rep];
        }
        uint4 m;
        m.x = rCM.x | rBM.x; m.y = rCM.y | rBM.y;
        m.z = rCM.z | rBM.z; m.w = rCM.w | rBM.w;
        *(uint4*)&Ma[mr * 64 + mc] = m;
    };

    float m_run[4], l_run[4];
    f32x4 accO[4];
    #pragma unroll
    for (int x = 0; x < 4; ++x) {
        m_run[x] = -__builtin_inff(); l_run[x] = 0.f;
        accO[x] = (f32x4){0.f, 0.f, 0.f, 0.f};
    }

    load_tiles(0);
    for (int jt = 0; jt < 8; ++jt) {
        const int j0 = jt * 64;
        __syncthreads();                              // A: prev PV/frag reads done
        store_tiles();
        __syncthreads();                              // B: staging visible
        if (jt < 7) load_tiles(jt + 1);               // prefetch next tile (regs)

        f16x8 afQ[2], afV[2];
        #pragma unroll
        for (int ks = 0; ks < 2; ++ks) {
            afQ[ks] = *(const f16x8*)&Qa[(w * 16 + l15) * 72 + ks * 32 + quad * 8];
            afV[ks] = afQ[ks] + dpbf[ks];
        }
        f32x4 accAC[4], accBD[8];
        #pragma unroll
        for (int nt = 0; nt < 4; ++nt) {
            accAC[nt] = (f32x4){0.f, 0.f, 0.f, 0.f};
            #pragma unroll
            for (int ks = 0; ks < 2; ++ks) {
                const f16x8 bf = *(const f16x8*)&Ka[(nt * 16 + l15) * 72 + ks * 32 + quad * 8];
                accAC[nt] = __builtin_amdgcn_mfma_f32_16x16x32_f16(afQ[ks], bf, accAC[nt], 0, 0, 0);
            }
        }
        #pragma unroll
        for (int nt = 0; nt < 8; ++nt) {
            accBD[nt] = (f32x4){0.f, 0.f, 0.f, 0.f};
            #pragma unroll
            for (int ks = 0; ks < 2; ++ks) {
                const f16x8 bf = *(const f16x8*)&Pa[(nt * 16 + l15) * 72 + ks * 32 + quad * 8];
                accBD[nt] = __builtin_amdgcn_mfma_f32_16x16x32_f16(afV[ks], bf, accBD[nt], 0, 0, 0);
            }
        }
        __syncthreads();                              // C: Pa/Ka frag reads done
        f16* BDW = Pa;
        #pragma unroll
        for (int nt = 0; nt < 8; ++nt) {
            f16x4 pk;
            #pragma unroll
            for (int rg = 0; rg < 4; ++rg) pk[rg] = (f16)accBD[nt][rg];
            *(f16x4*)&BDW[(nt * 16 + l15) * 68 + rowt] = pk;
        }
        __syncthreads();                              // D: BDW visible

        // gather + mask (LDS) + online softmax; W -> Ka slot
        #pragma unroll
        for (int rg = 0; rg < 4; ++rg) {
            const int rt = rowt + rg;
            float sv[4]; unsigned mk = 0;
            #pragma unroll
            for (int nt = 0; nt < 4; ++nt) {
                const int c = nt * 16 + l15;
                const int nw = c - rt + 63;
                float s = (accAC[nt][rg] + (float)BDW[nw * 68 + rt]) * 0.125f;
                if (Ma[rt * 64 + c]) { s = -3.402823466e38f; mk |= 1u << nt; }
                sv[nt] = s;
            }
            float tmax = fmaxf(fmaxf(sv[0], sv[1]), fmaxf(sv[2], sv[3]));
            #pragma unroll
            for (int d = 1; d < 16; d <<= 1) tmax = fmaxf(tmax, __shfl_xor(tmax, d));
            const float mnew = fmaxf(m_run[rg], tmax);
            const float alpha = __expf(m_run[rg] - mnew);
            float rsum = 0.f;
            f16 wv[4];
            #pragma unroll
            for (int nt = 0; nt < 4; ++nt) {
                const float e = __expf(sv[nt] - mnew);
                rsum += e;                                      // denom over all j (ref)
                wv[nt] = ((mk >> nt) & 1u) ? (f16)0.f : (f16)e; // zero masked for PV
            }
            #pragma unroll
            for (int d = 1; d < 16; d <<= 1) rsum += __shfl_xor(rsum, d);
            l_run[rg] = l_run[rg] * alpha + rsum;
            m_run[rg] = mnew;
            #pragma unroll
            for (int dt = 0; dt < 4; ++dt) accO[dt][rg] *= alpha;
            #pragma unroll
            for (int nt = 0; nt < 4; ++nt)
                Ka[rt * 72 + nt * 16 + l15] = wv[nt];
        }
        __syncthreads();                              // E: W visible
        f16x8 afW[2];
        #pragma unroll
        for (int ks = 0; ks < 2; ++ks)
            afW[ks] = *(const f16x8*)&Ka[(w * 16 + l15) * 72 + ks * 32 + quad * 8];
        #pragma unroll
        for (int dt = 0; dt < 4; ++dt)
            #pragma unroll
            for (int ks = 0; ks < 2; ++ks) {
                const f16x8 bf = *(const f16x8*)&Va[(dt * 16 + l15) * 72 + ks * 32 + quad * 8];
                accO[dt] = __builtin_amdgcn_mfma_f32_16x16x32_f16(afW[ks], bf, accO[dt], 0, 0, 0);
            }
    }

    #pragma unroll
    for (int rg = 0; rg < 4; ++rg) {
        const float inv = 1.0f / l_run[rg];
        const int gi = i0 + rowt + rg;
        #pragma unroll
        for (int dt = 0; dt < 4; ++dt)
            CTX[((size_t)b * 512 + gi) * 512 + h * 64 + dt * 16 + l15] = (f16)(accO[dt][rg] * inv);
    }
}

extern "C" void kernel_launch(void* const* d_in, const int* in_sizes, int n_in,
                              void* d_out, int out_size, void* d_ws, size_t ws_size,
                              hipStream_t stream) {
    const float* query   = (const float*)d_in[0];
    const float* key     = (const float*)d_in[1];
    const float* value   = (const float*)d_in[2];
    const float* pos_enc = (const float*)d_in[3];
    const unsigned char* mask       = (const unsigned char*)d_in[4];
    const unsigned char* chunk_mask = (const unsigned char*)d_in[5];
    const float* Wq  = (const float*)d_in[6];
    const float* bq  = (const float*)d_in[7];
    const float* Wk  = (const float*)d_in[8];
    const float* bk  = (const float*)d_in[9];
    const float* Wv  = (const float*)d_in[10];
    const float* bv  = (const float*)d_in[11];
    const float* Wpos = (const float*)d_in[12];
    const float* Wo   = (const float*)d_in[13];
    const float* bo   = (const float*)d_in[14];
    const float* pbu  = (const float*)d_in[15];
    const float* pbv  = (const float*)d_in[16];
    float* out = (float*)d_out;

    f16* base = (f16*)d_ws;
    size_t off = 0;
    f16* ctx = base + off; off += 4194304;   // (B,T1,E) f16 attn output
    f16* Qhm = base + off; off += 4194304;   // (B,H,T1,DK)  q+bq+pbu
    f16* Khm = base + off; off += 4194304;   // (B,H,T2,DK)
    f16* Vtm = base + off; off += 4194304;   // (B,H,DK,T2)
    f16* Phm = base + off; off += 8380416;   // (B,H,NPOS,DK)

    PArg4 pa;
    pa.g[0] = PArg{query,   Wq,   bq, pbu,     (void*)Qhm, 8192,  2, 0};
    pa.g[1] = PArg{key,     Wk,   bk, nullptr, (void*)Khm, 8192,  2, 0};
    pa.g[2] = PArg{value,   Wv,   bv, nullptr, (void*)Vtm, 8192,  1, 0};
    pa.g[3] = PArg{pos_enc, Wpos, nullptr, nullptr, (void*)Phm, 16368, 3, 0};
    proj_fused<<<dim3(1280), 256, 0, stream>>>(pa);

    attn_mfma<<<dim3(8, 8, 16), 256, 0, stream>>>(Qhm, Khm, Vtm, Phm, pbu, pbv,
                                                  mask, chunk_mask, ctx);

    PArg go = PArg{ctx, Wo, bo, nullptr, (void*)out, 8192, 0, 1};
    proj_one<<<dim3(4, 64), 256, 0, stream>>>(go);
}

// Round 6
// 320.105 us; speedup vs baseline: 1.0870x; 1.0870x over previous
//
#include <hip/hip_runtime.h>
#include <math.h>

typedef _Float16 f16;
typedef f16 f16x8 __attribute__((ext_vector_type(8)));
typedef f16 f16x4 __attribute__((ext_vector_type(4)));
typedef float f32x4 __attribute__((ext_vector_type(4)));

#define H_   8
#define E_   512
#define DK   64
#define BB   16
#define T1C  512
#define T2C  512
#define NPOS 1023

// ---------------- cast fp32 -> fp16 (zero-pad to ndst) ----------------
struct CastDesc {
    const float* src[9];
    f16* dst[9];
    int nsrc[9];
    int ndst[9];
};
__global__ __launch_bounds__(256) void cast_f32_f16(CastDesc cd) {
    const int s = blockIdx.y;
    const float* sp = cd.src[s];
    f16* dp = cd.dst[s];
    const int n4 = cd.ndst[s] >> 2;
    const int ns = cd.nsrc[s];
    for (int i = blockIdx.x * 256 + threadIdx.x; i < n4; i += gridDim.x * 256) {
        const int base = i * 4;
        float4 v = make_float4(0.f, 0.f, 0.f, 0.f);
        if (base < ns) v = *(const float4*)(sp + base);
        f16x4 h; h[0] = (f16)v.x; h[1] = (f16)v.y; h[2] = (f16)v.z; h[3] = (f16)v.w;
        *(f16x4*)(dp + base) = h;
    }
}

// ---------------- f16 MFMA GEMM, 64x64 tile (high block-parallelism) ----------------
// C = A(M,512) @ W(512,512)^T + bias (+bias2)
// modes: 0 fp32 row-major (M,512) | 1 f16 (B,H,DK,512) | 2 f16 (B,H,512,DK) | 3 f16 (B,H,NPOS,DK)
struct PArg {
    const f16* A; const f16* W; const float* bias; const float* bias2;
    void* C; int Mvalid; int mode;
};
struct PArgs { PArg g[4]; };

__device__ __forceinline__ void gemm64_body(const PArg g, int bx, int by) {
    __shared__ f16 Al[64 * 40];
    __shared__ f16 Wl[64 * 40];
    const int tid = threadIdx.x;
    const int lane = tid & 63, w = tid >> 6;
    const int quad = lane >> 4, l15 = lane & 15;
    const int m0 = by * 64, n0 = bx * 64;
    const int row = tid >> 2, koff = (tid & 3) * 8;

    f32x4 acc[4];
    #pragma unroll
    for (int nt = 0; nt < 4; ++nt) acc[nt] = (f32x4){0.f, 0.f, 0.f, 0.f};

    const size_t aoff = (size_t)(m0 + row) * 512;
    const size_t woff = (size_t)(n0 + row) * 512;

    for (int k0 = 0; k0 < 512; k0 += 32) {
        const uint4 av = *(const uint4*)&g.A[aoff + k0 + koff];
        const uint4 wv = *(const uint4*)&g.W[woff + k0 + koff];
        __syncthreads();
        *(uint4*)&Al[row * 40 + koff] = av;
        *(uint4*)&Wl[row * 40 + koff] = wv;
        __syncthreads();
        const f16x8 af = *(const f16x8*)&Al[(w * 16 + l15) * 40 + quad * 8];
        #pragma unroll
        for (int nt = 0; nt < 4; ++nt) {
            const f16x8 bf = *(const f16x8*)&Wl[(nt * 16 + l15) * 40 + quad * 8];
            acc[nt] = __builtin_amdgcn_mfma_f32_16x16x32_f16(af, bf, acc[nt], 0, 0, 0);
        }
    }

    // C/D layout: col = lane&15, row = (lane>>4)*4 + reg
    const int mb = m0 + w * 16 + quad * 4;
    #pragma unroll
    for (int nt = 0; nt < 4; ++nt) {
        const int n = n0 + nt * 16 + l15;
        const f32x4 a = acc[nt];
        float bs = g.bias ? g.bias[n] : 0.f;
        if (g.bias2) bs += g.bias2[n];
        if (g.mode == 0) {
            float* C = (float*)g.C;
            #pragma unroll
            for (int r = 0; r < 4; ++r) C[(size_t)(mb + r) * 512 + n] = a[r] + bs;
        } else if (g.mode == 1) {
            f16* C = (f16*)g.C;
            const int b = mb >> 9, t = mb & 511;
            const int hh = n >> 6, dk = n & 63;
            f16x4 h;
            #pragma unroll
            for (int r = 0; r < 4; ++r) h[r] = (f16)(a[r] + bs);
            *(f16x4*)&C[(((size_t)b * H_ + hh) * DK + dk) * 512 + t] = h;
        } else if (g.mode == 2) {
            f16* C = (f16*)g.C;
            const int b = mb >> 9, t = mb & 511;
            const int hh = n >> 6, dk = n & 63;
            #pragma unroll
            for (int r = 0; r < 4; ++r)
                C[(((size_t)b * H_ + hh) * 512 + t + r) * DK + dk] = (f16)(a[r] + bs);
        } else {
            f16* C = (f16*)g.C;
            const int hh = n >> 6, dk = n & 63;
            #pragma unroll
            for (int r = 0; r < 4; ++r) {
                const int m = mb + r;
                if (m < g.Mvalid) {
                    const int b = m / NPOS, t = m - b * NPOS;
                    C[(((size_t)b * H_ + hh) * NPOS + t) * DK + dk] = (f16)a[r];
                }
            }
        }
    }
}

// fused: QKV (3 x 1024 blocks) + Pos (2048 blocks)
__global__ __launch_bounds__(256) void proj_all(PArgs a) {
    const int id = blockIdx.x;
    int gi, rem;
    if (id < 3072) { gi = id >> 10; rem = id & 1023; }
    else           { gi = 3;        rem = id - 3072; }
    gemm64_body(a.g[gi], rem & 7, rem >> 3);
}
__global__ __launch_bounds__(256) void proj_one(PArg g) {
    gemm64_body(g, blockIdx.x & 7, blockIdx.x >> 3);
}

// ---------------- MFMA flash attention with rel-shift via ds_permute ----------------
// Block = (64-row i-tile, h, b); 4 waves; wave w owns rows [w*16, w*16+16).
// 3 barriers per j-tile. Rel-shift gather: quad-local push permute of accBD.
// LDS: Qa 9216 + Ka 9216 (reused for W, wave-own rows) + Va 9216 + Pa 18432 + Ma 4096 = 50176 B
__global__ __launch_bounds__(256) void attn_mfma(
    const f16* __restrict__ Qh,   // (B,H,T1,DK) = q + bq + pbu
    const f16* __restrict__ Kh,   // (B,H,T2,DK)
    const f16* __restrict__ Vt,   // (B,H,DK,T2)
    const f16* __restrict__ Ph,   // (B,H,NPOS,DK)
    const float* __restrict__ pbu, const float* __restrict__ pbv,
    const unsigned char* __restrict__ bmask,   // (B,T2)
    const unsigned char* __restrict__ cmask,   // (T1,T1)
    f16* __restrict__ CTX)        // (B,T1,E) f16
{
    __shared__ f16 Qa[64 * 72];
    __shared__ f16 Ka[64 * 72];             // K tile; W written into wave-own rows
    __shared__ f16 Va[64 * 72];             // V^T tile [d][j]
    __shared__ f16 Pa[128 * 72];            // P window [nw][d]
    __shared__ unsigned char Ma[64 * 64];   // combined mask tile [r][c]

    const int tid = threadIdx.x;
    const int lane = tid & 63, w = tid >> 6;
    const int quad = lane >> 4, l15 = lane & 15;
    const int it = blockIdx.x, h = blockIdx.y, b = blockIdx.z;
    const int i0 = it * 64;
    const int bh = b * H_ + h;
    const int rowt = w * 16 + quad * 4;     // tile-local row base of this lane

    // stage Q tile (pbu/bq pre-folded by proj)
    #pragma unroll
    for (int rep = 0; rep < 2; ++rep) {
        const int flat = rep * 2048 + tid * 8;
        const int r = flat >> 6, c = flat & 63;
        *(uint4*)&Qa[r * 72 + c] = *(const uint4*)&Qh[((size_t)bh * 512 + i0 + r) * 64 + c];
    }
    // (pbv - pbu) A-frag correction at k = ks*32 + quad*8 + j
    f16x8 dpbf[2];
    #pragma unroll
    for (int ks = 0; ks < 2; ++ks)
        #pragma unroll
        for (int j = 0; j < 8; ++j) {
            const int d = ks * 32 + quad * 8 + j;
            dpbf[ks][j] = (f16)(pbv[h * 64 + d] - pbu[h * 64 + d]);
        }

    float m_run[4], l_run[4];
    f32x4 accO[4];
    #pragma unroll
    for (int x = 0; x < 4; ++x) {
        m_run[x] = -__builtin_inff(); l_run[x] = 0.f;
        accO[x] = (f32x4){0.f, 0.f, 0.f, 0.f};
    }

    const int mr = tid >> 2, mc = (tid & 3) * 16;

    for (int jt = 0; jt < 8; ++jt) {
        const int j0 = jt * 64;
        const int nbase = j0 - i0 + 448;              // [0, 896]
        __syncthreads();                              // A: prev tile's reads done
        #pragma unroll
        for (int rep = 0; rep < 2; ++rep) {
            const int flat = rep * 2048 + tid * 8;
            const int r = flat >> 6, c = flat & 63;
            *(uint4*)&Ka[r * 72 + c] = *(const uint4*)&Kh[((size_t)bh * 512 + j0 + r) * 64 + c];
            *(uint4*)&Va[r * 72 + c] = *(const uint4*)&Vt[((size_t)bh * 64 + r) * 512 + j0 + c];
        }
        #pragma unroll
        for (int rep = 0; rep < 4; ++rep) {
            const int flat = rep * 2048 + tid * 8;
            const int nw = flat >> 6, c = flat & 63;
            int n = nbase + nw; n = n > (NPOS - 1) ? (NPOS - 1) : n;  // nw=127 never gathered
            *(uint4*)&Pa[nw * 72 + c] = *(const uint4*)&Ph[((size_t)bh * NPOS + n) * 64 + c];
        }
        {
            const uint4 cm = *(const uint4*)&cmask[(size_t)(i0 + mr) * 512 + j0 + mc];
            const uint4 bm = *(const uint4*)&bmask[(size_t)b * 512 + j0 + mc];
            uint4 mm;
            mm.x = cm.x | bm.x; mm.y = cm.y | bm.y;
            mm.z = cm.z | bm.z; mm.w = cm.w | bm.w;
            *(uint4*)&Ma[mr * 64 + mc] = mm;
        }
        __syncthreads();                              // B: staging visible

        f16x8 afQ[2], afV[2];
        #pragma unroll
        for (int ks = 0; ks < 2; ++ks) {
            afQ[ks] = *(const f16x8*)&Qa[(w * 16 + l15) * 72 + ks * 32 + quad * 8];
            afV[ks] = afQ[ks] + dpbf[ks];
        }
        // AC: 4 blocks x 2 ks
        f32x4 accAC[4];
        #pragma unroll
        for (int nt = 0; nt < 4; ++nt) {
            accAC[nt] = (f32x4){0.f, 0.f, 0.f, 0.f};
            #pragma unroll
            for (int ks = 0; ks < 2; ++ks) {
                const f16x8 bf = *(const f16x8*)&Ka[(nt * 16 + l15) * 72 + ks * 32 + quad * 8];
                accAC[nt] = __builtin_amdgcn_mfma_f32_16x16x32_f16(afQ[ks], bf, accAC[nt], 0, 0, 0);
            }
        }
        // BD: wave-private 79-wide window -> 5 blocks (nw blocks 3-w .. 7-w)
        f32x4 accBD[5];
        #pragma unroll
        for (int u = 0; u < 5; ++u) {
            accBD[u] = (f32x4){0.f, 0.f, 0.f, 0.f};
            const int nts = (3 - w) + u;
            #pragma unroll
            for (int ks = 0; ks < 2; ++ks) {
                const f16x8 bf = *(const f16x8*)&Pa[(nts * 16 + l15) * 72 + ks * 32 + quad * 8];
                accBD[u] = __builtin_amdgcn_mfma_f32_16x16x32_f16(afV[ks], bf, accBD[u], 0, 0, 0);
            }
        }
        __syncthreads();                              // C: Ka/Pa frag reads done (W may overwrite Ka)

        // gather (quad-local push permute) + mask + online softmax; W -> Ka wave-own rows
        #pragma unroll
        for (int rg = 0; rg < 4; ++rg) {
            const int qr = quad * 4 + rg;             // quad-local row 0..15
            const int rt = rowt + rg;                 // tile-local row
            // push: lane l15 holds BDW[rt][(3-w+u)*16 + l15]; dest c = l15 + C_u
            float tmpv[5];
            #pragma unroll
            for (int u = 0; u < 5; ++u) {
                const int cl = l15 + (3 + u) * 16 + qr - 63;
                const int dst = (quad * 16 + (cl & 15)) << 2;
                tmpv[u] = __uint_as_float(
                    (unsigned)__builtin_amdgcn_ds_permute(dst, (int)__float_as_uint(accBD[u][rg])));
            }
            const bool hi = l15 > qr;                 // u = nt + (l15 > qr)
            float sv[4]; unsigned mk = 0;
            #pragma unroll
            for (int nt = 0; nt < 4; ++nt) {
                const int c = nt * 16 + l15;
                const float bdv = hi ? tmpv[nt + 1] : tmpv[nt];
                float s = (accAC[nt][rg] + bdv) * 0.125f;
                if (Ma[rt * 64 + c]) { s = -3.402823466e38f; mk |= 1u << nt; }
                sv[nt] = s;
            }
            float tmax = fmaxf(fmaxf(sv[0], sv[1]), fmaxf(sv[2], sv[3]));
            #pragma unroll
            for (int d = 1; d < 16; d <<= 1) tmax = fmaxf(tmax, __shfl_xor(tmax, d));
            const float mnew = fmaxf(m_run[rg], tmax);
            const float alpha = __expf(m_run[rg] - mnew);
            float rsum = 0.f;
            f16 wv[4];
            #pragma unroll
            for (int nt = 0; nt < 4; ++nt) {
                const float e = __expf(sv[nt] - mnew);
                rsum += e;                                      // denom over all j (ref semantics)
                wv[nt] = ((mk >> nt) & 1u) ? (f16)0.f : (f16)e; // zero masked for PV
            }
            #pragma unroll
            for (int d = 1; d < 16; d <<= 1) rsum += __shfl_xor(rsum, d);
            l_run[rg] = l_run[rg] * alpha + rsum;
            m_run[rg] = mnew;
            #pragma unroll
            for (int dt = 0; dt < 4; ++dt) accO[dt][rg] *= alpha;
            #pragma unroll
            for (int nt = 0; nt < 4; ++nt)
                Ka[rt * 72 + nt * 16 + l15] = wv[nt];
        }
        // PV: afW reads wave-own Ka rows (same-wave write -> lgkmcnt, no barrier)
        f16x8 afW[2];
        #pragma unroll
        for (int ks = 0; ks < 2; ++ks)
            afW[ks] = *(const f16x8*)&Ka[(w * 16 + l15) * 72 + ks * 32 + quad * 8];
        #pragma unroll
        for (int dt = 0; dt < 4; ++dt)
            #pragma unroll
            for (int ks = 0; ks < 2; ++ks) {
                const f16x8 bf = *(const f16x8*)&Va[(dt * 16 + l15) * 72 + ks * 32 + quad * 8];
                accO[dt] = __builtin_amdgcn_mfma_f32_16x16x32_f16(afW[ks], bf, accO[dt], 0, 0, 0);
            }
    }

    #pragma unroll
    for (int rg = 0; rg < 4; ++rg) {
        const float inv = 1.0f / l_run[rg];
        const int gi = i0 + rowt + rg;
        #pragma unroll
        for (int dt = 0; dt < 4; ++dt)
            CTX[((size_t)b * 512 + gi) * 512 + h * 64 + dt * 16 + l15] = (f16)(accO[dt][rg] * inv);
    }
}

extern "C" void kernel_launch(void* const* d_in, const int* in_sizes, int n_in,
                              void* d_out, int out_size, void* d_ws, size_t ws_size,
                              hipStream_t stream) {
    const float* query   = (const float*)d_in[0];
    const float* key     = (const float*)d_in[1];
    const float* value   = (const float*)d_in[2];
    const float* pos_enc = (const float*)d_in[3];
    const unsigned char* mask       = (const unsigned char*)d_in[4];
    const unsigned char* chunk_mask = (const unsigned char*)d_in[5];
    const float* Wq  = (const float*)d_in[6];
    const float* bq  = (const float*)d_in[7];
    const float* Wk  = (const float*)d_in[8];
    const float* bk  = (const float*)d_in[9];
    const float* Wv  = (const float*)d_in[10];
    const float* bv  = (const float*)d_in[11];
    const float* Wpos = (const float*)d_in[12];
    const float* Wo   = (const float*)d_in[13];
    const float* bo   = (const float*)d_in[14];
    const float* pbu  = (const float*)d_in[15];
    const float* pbv  = (const float*)d_in[16];
    float* out = (float*)d_out;

    f16* base = (f16*)d_ws;
    size_t off = 0;
    f16* qh  = base + off; off += 4194304;   // f16 inputs
    f16* kh  = base + off; off += 4194304;
    f16* vh  = base + off; off += 4194304;
    f16* ph  = base + off; off += 8388608;   // padded to 16384 rows
    f16* wqh = base + off; off += 262144;
    f16* wkh = base + off; off += 262144;
    f16* wvh = base + off; off += 262144;
    f16* wph = base + off; off += 262144;
    f16* woh = base + off; off += 262144;
    f16* ctx = base + off; off += 4194304;   // (B,T1,E) attn output
    f16* Qhm = base + off; off += 4194304;   // (B,H,T1,DK)  q+bq+pbu
    f16* Khm = base + off; off += 4194304;   // (B,H,T2,DK)
    f16* Vtm = base + off; off += 4194304;   // (B,H,DK,T2)
    f16* Phm = base + off; off += 8380416;   // (B,H,NPOS,DK)

    CastDesc cd;
    cd.src[0] = query;   cd.dst[0] = qh;  cd.nsrc[0] = 4194304; cd.ndst[0] = 4194304;
    cd.src[1] = key;     cd.dst[1] = kh;  cd.nsrc[1] = 4194304; cd.ndst[1] = 4194304;
    cd.src[2] = value;   cd.dst[2] = vh;  cd.nsrc[2] = 4194304; cd.ndst[2] = 4194304;
    cd.src[3] = pos_enc; cd.dst[3] = ph;  cd.nsrc[3] = 8380416; cd.ndst[3] = 8388608;
    cd.src[4] = Wq;   cd.dst[4] = wqh; cd.nsrc[4] = 262144; cd.ndst[4] = 262144;
    cd.src[5] = Wk;   cd.dst[5] = wkh; cd.nsrc[5] = 262144; cd.ndst[5] = 262144;
    cd.src[6] = Wv;   cd.dst[6] = wvh; cd.nsrc[6] = 262144; cd.ndst[6] = 262144;
    cd.src[7] = Wpos; cd.dst[7] = wph; cd.nsrc[7] = 262144; cd.ndst[7] = 262144;
    cd.src[8] = Wo;   cd.dst[8] = woh; cd.nsrc[8] = 262144; cd.ndst[8] = 262144;
    cast_f32_f16<<<dim3(256, 9), 256, 0, stream>>>(cd);

    PArgs pa;
    pa.g[0] = PArg{qh, wqh, bq, pbu,     (void*)Qhm, 8192,  2};
    pa.g[1] = PArg{kh, wkh, bk, nullptr, (void*)Khm, 8192,  2};
    pa.g[2] = PArg{vh, wvh, bv, nullptr, (void*)Vtm, 8192,  1};
    pa.g[3] = PArg{ph, wph, nullptr, nullptr, (void*)Phm, 16368, 3};
    proj_all<<<dim3(5120), 256, 0, stream>>>(pa);

    attn_mfma<<<dim3(8, 8, 16), 256, 0, stream>>>(Qhm, Khm, Vtm, Phm, pbu, pbv,
                                                  mask, chunk_mask, ctx);

    PArg go = PArg{ctx, woh, bo, nullptr, (void*)out, 8192, 0};
    proj_one<<<dim3(1024), 256, 0, stream>>>(go);
}

// Round 7
// 316.576 us; speedup vs baseline: 1.0991x; 1.0111x over previous
//
#include <hip/hip_runtime.h>
#include <math.h>

typedef _Float16 f16;
typedef f16 f16x8 __attribute__((ext_vector_type(8)));
typedef f16 f16x4 __attribute__((ext_vector_type(4)));
typedef float f32x4 __attribute__((ext_vector_type(4)));

#define H_   8
#define E_   512
#define DK   64
#define BB   16
#define T1C  512
#define T2C  512
#define NPOS 1023

__device__ __forceinline__ f16x8 cvt8(const float4 a, const float4 b) {
    f16x8 h;
    h[0] = (f16)a.x; h[1] = (f16)a.y; h[2] = (f16)a.z; h[3] = (f16)a.w;
    h[4] = (f16)b.x; h[5] = (f16)b.y; h[6] = (f16)b.z; h[7] = (f16)b.w;
    return h;
}

// ---------------- f16 MFMA GEMM, 64x64 tile, fp32 inputs converted in-register ----------------
// C = A(M,512) @ W(512,512)^T + bias (+bias2). A fp32 (a16=0) or f16 (a16=1); W fp32.
// Register-prefetched k-loop (1 k-step lookahead), 2 barriers/k-step but latency hidden.
// modes: 0 fp32 row-major (M,512) | 1 f16 (B,H,DK,512) | 2 f16 (B,H,512,DK) | 3 f16 (B,H,NPOS,DK)
struct PArg {
    const void* A; const float* W; const float* bias; const float* bias2;
    void* C; int Mvalid; int mode; int a16;
};
struct PArgs { PArg g[4]; };

__device__ __forceinline__ void gemm64_body(const PArg g, int bx, int by) {
    __shared__ f16 Al[64 * 40];
    __shared__ f16 Wl[64 * 40];
    const int tid = threadIdx.x;
    const int lane = tid & 63, w = tid >> 6;
    const int quad = lane >> 4, l15 = lane & 15;
    const int m0 = by * 64, n0 = bx * 64;
    const int row = tid >> 2, koff = (tid & 3) * 8;
    int arow = m0 + row; if (arow >= g.Mvalid) arow = g.Mvalid - 1;  // clamp (pos tail)
    const size_t aoff = (size_t)arow * 512 + koff;
    const size_t woff = (size_t)(n0 + row) * 512 + koff;

    f32x4 acc[4];
    #pragma unroll
    for (int nt = 0; nt < 4; ++nt) acc[nt] = (f32x4){0.f, 0.f, 0.f, 0.f};

    float4 fa0, fa1, fw0, fw1;
    uint4 ha;
    if (g.a16) {
        ha = *(const uint4*)((const f16*)g.A + aoff);
    } else {
        fa0 = *(const float4*)((const float*)g.A + aoff);
        fa1 = *(const float4*)((const float*)g.A + aoff + 4);
    }
    fw0 = *(const float4*)(g.W + woff);
    fw1 = *(const float4*)(g.W + woff + 4);

    for (int ki = 0; ki < 16; ++ki) {
        __syncthreads();                       // frag reads of ki-1 done
        if (g.a16) *(uint4*)&Al[row * 40 + koff] = ha;
        else       *(f16x8*)&Al[row * 40 + koff] = cvt8(fa0, fa1);
        *(f16x8*)&Wl[row * 40 + koff] = cvt8(fw0, fw1);
        __syncthreads();                       // stores visible
        if (ki < 15) {                         // prefetch next k-step (hidden behind MFMA)
            const int k0 = (ki + 1) * 32;
            if (g.a16) {
                ha = *(const uint4*)((const f16*)g.A + aoff + k0);
            } else {
                fa0 = *(const float4*)((const float*)g.A + aoff + k0);
                fa1 = *(const float4*)((const float*)g.A + aoff + k0 + 4);
            }
            fw0 = *(const float4*)(g.W + woff + k0);
            fw1 = *(const float4*)(g.W + woff + k0 + 4);
        }
        const f16x8 af = *(const f16x8*)&Al[(w * 16 + l15) * 40 + quad * 8];
        #pragma unroll
        for (int nt = 0; nt < 4; ++nt) {
            const f16x8 bf = *(const f16x8*)&Wl[(nt * 16 + l15) * 40 + quad * 8];
            acc[nt] = __builtin_amdgcn_mfma_f32_16x16x32_f16(af, bf, acc[nt], 0, 0, 0);
        }
    }

    // C/D layout: col = lane&15, row = (lane>>4)*4 + reg
    const int mb = m0 + w * 16 + quad * 4;
    #pragma unroll
    for (int nt = 0; nt < 4; ++nt) {
        const int n = n0 + nt * 16 + l15;
        const f32x4 a = acc[nt];
        float bs = g.bias ? g.bias[n] : 0.f;
        if (g.bias2) bs += g.bias2[n];
        if (g.mode == 0) {
            float* C = (float*)g.C;
            #pragma unroll
            for (int r = 0; r < 4; ++r) C[(size_t)(mb + r) * 512 + n] = a[r] + bs;
        } else if (g.mode == 1) {
            f16* C = (f16*)g.C;
            const int b = mb >> 9, t = mb & 511;
            const int hh = n >> 6, dk = n & 63;
            f16x4 h;
            #pragma unroll
            for (int r = 0; r < 4; ++r) h[r] = (f16)(a[r] + bs);
            *(f16x4*)&C[(((size_t)b * H_ + hh) * DK + dk) * 512 + t] = h;
        } else if (g.mode == 2) {
            f16* C = (f16*)g.C;
            const int b = mb >> 9, t = mb & 511;
            const int hh = n >> 6, dk = n & 63;
            #pragma unroll
            for (int r = 0; r < 4; ++r)
                C[(((size_t)b * H_ + hh) * 512 + t + r) * DK + dk] = (f16)(a[r] + bs);
        } else {
            f16* C = (f16*)g.C;
            const int hh = n >> 6, dk = n & 63;
            #pragma unroll
            for (int r = 0; r < 4; ++r) {
                const int m = mb + r;
                if (m < g.Mvalid) {
                    const int b = m / NPOS, t = m - b * NPOS;
                    C[(((size_t)b * H_ + hh) * NPOS + t) * DK + dk] = (f16)a[r];
                }
            }
        }
    }
}

// fused: Q (1024) | K (1024) | V (1024) | Pos (2048)
__global__ __launch_bounds__(256) void proj_all(PArgs a) {
    const int id = blockIdx.x;
    int gi, rem;
    if (id < 3072) { gi = id >> 10; rem = id & 1023; }
    else           { gi = 3;        rem = id - 3072; }
    gemm64_body(a.g[gi], rem & 7, rem >> 3);
}
__global__ __launch_bounds__(256) void proj_one(PArg g) {
    gemm64_body(g, blockIdx.x & 7, blockIdx.x >> 3);
}

// ---------------- MFMA flash attention with rel-shift via ds_permute ----------------
// Block = (64-row i-tile, h, b); 4 waves; wave w owns rows [w*16, w*16+16).
// Register prefetch of next j-tile (K/V/P/mask) during compute; 3 barriers per j-tile.
// LDS: Qa 9216 + Ka 9216 (reused for W, wave-own rows) + Va 9216 + Pa 18432 + Ma 4096 = 50176 B
__global__ __launch_bounds__(256) void attn_mfma(
    const f16* __restrict__ Qh,   // (B,H,T1,DK) = q + bq + pbu
    const f16* __restrict__ Kh,   // (B,H,T2,DK)
    const f16* __restrict__ Vt,   // (B,H,DK,T2)
    const f16* __restrict__ Ph,   // (B,H,NPOS,DK)
    const float* __restrict__ pbu, const float* __restrict__ pbv,
    const unsigned char* __restrict__ bmask,   // (B,T2)
    const unsigned char* __restrict__ cmask,   // (T1,T1)
    f16* __restrict__ CTX)        // (B,T1,E) f16
{
    __shared__ f16 Qa[64 * 72];
    __shared__ f16 Ka[64 * 72];             // K tile; W written into wave-own rows
    __shared__ f16 Va[64 * 72];             // V^T tile [d][j]
    __shared__ f16 Pa[128 * 72];            // P window [nw][d]
    __shared__ unsigned char Ma[64 * 64];   // combined mask tile [r][c]

    const int tid = threadIdx.x;
    const int lane = tid & 63, w = tid >> 6;
    const int quad = lane >> 4, l15 = lane & 15;
    const int it = blockIdx.x, h = blockIdx.y, b = blockIdx.z;
    const int i0 = it * 64;
    const int bh = b * H_ + h;
    const int rowt = w * 16 + quad * 4;     // tile-local row base of this lane
    const int sr = tid >> 3, sc = (tid & 7) * 8;   // staging row/col (8 lanes per 64-col row)
    const int mr = tid >> 2, mc = (tid & 3) * 16;  // mask staging

    // stage Q tile (pbu/bq pre-folded by proj)
    *(uint4*)&Qa[sr * 72 + sc] = *(const uint4*)&Qh[((size_t)bh * 512 + i0 + sr) * 64 + sc];
    *(uint4*)&Qa[(sr + 32) * 72 + sc] =
        *(const uint4*)&Qh[((size_t)bh * 512 + i0 + sr + 32) * 64 + sc];
    // (pbv - pbu) A-frag correction at k = ks*32 + quad*8 + j
    f16x8 dpbf[2];
    #pragma unroll
    for (int ks = 0; ks < 2; ++ks)
        #pragma unroll
        for (int j = 0; j < 8; ++j) {
            const int d = ks * 32 + quad * 8 + j;
            dpbf[ks][j] = (f16)(pbv[h * 64 + d] - pbu[h * 64 + d]);
        }

    float m_run[4], l_run[4];
    f32x4 accO[4];
    #pragma unroll
    for (int x = 0; x < 4; ++x) {
        m_run[x] = -__builtin_inff(); l_run[x] = 0.f;
        accO[x] = (f32x4){0.f, 0.f, 0.f, 0.f};
    }

    // ---- explicit prefetch registers (NO arrays/lambdas: avoid scratch spill) ----
    uint4 pK0, pK1, pV0, pV1, pP0, pP1, pP2, pP3, pM;
    {
        const int j0 = 0, nbase = 448 - i0;
        pK0 = *(const uint4*)&Kh[((size_t)bh * 512 + j0 + sr) * 64 + sc];
        pK1 = *(const uint4*)&Kh[((size_t)bh * 512 + j0 + sr + 32) * 64 + sc];
        pV0 = *(const uint4*)&Vt[((size_t)bh * 64 + sr) * 512 + j0 + sc];
        pV1 = *(const uint4*)&Vt[((size_t)bh * 64 + sr + 32) * 512 + j0 + sc];
        int n0_ = nbase + sr;       if (n0_ > NPOS - 1) n0_ = NPOS - 1;
        int n1_ = nbase + sr + 32;  if (n1_ > NPOS - 1) n1_ = NPOS - 1;
        int n2_ = nbase + sr + 64;  if (n2_ > NPOS - 1) n2_ = NPOS - 1;
        int n3_ = nbase + sr + 96;  if (n3_ > NPOS - 1) n3_ = NPOS - 1;
        pP0 = *(const uint4*)&Ph[((size_t)bh * NPOS + n0_) * 64 + sc];
        pP1 = *(const uint4*)&Ph[((size_t)bh * NPOS + n1_) * 64 + sc];
        pP2 = *(const uint4*)&Ph[((size_t)bh * NPOS + n2_) * 64 + sc];
        pP3 = *(const uint4*)&Ph[((size_t)bh * NPOS + n3_) * 64 + sc];
        const uint4 cm = *(const uint4*)&cmask[(size_t)(i0 + mr) * 512 + j0 + mc];
        const uint4 bm = *(const uint4*)&bmask[(size_t)b * 512 + j0 + mc];
        pM.x = cm.x | bm.x; pM.y = cm.y | bm.y; pM.z = cm.z | bm.z; pM.w = cm.w | bm.w;
    }

    for (int jt = 0; jt < 8; ++jt) {
        __syncthreads();                              // A: prev tile's frag reads done
        *(uint4*)&Ka[sr * 72 + sc] = pK0;
        *(uint4*)&Ka[(sr + 32) * 72 + sc] = pK1;
        *(uint4*)&Va[sr * 72 + sc] = pV0;
        *(uint4*)&Va[(sr + 32) * 72 + sc] = pV1;
        *(uint4*)&Pa[sr * 72 + sc] = pP0;
        *(uint4*)&Pa[(sr + 32) * 72 + sc] = pP1;
        *(uint4*)&Pa[(sr + 64) * 72 + sc] = pP2;
        *(uint4*)&Pa[(sr + 96) * 72 + sc] = pP3;
        *(uint4*)&Ma[mr * 64 + mc] = pM;
        __syncthreads();                              // B: staging visible

        if (jt < 7) {                                 // prefetch next j-tile during compute
            const int j0n = (jt + 1) * 64;
            const int nbase = j0n - i0 + 448;
            pK0 = *(const uint4*)&Kh[((size_t)bh * 512 + j0n + sr) * 64 + sc];
            pK1 = *(const uint4*)&Kh[((size_t)bh * 512 + j0n + sr + 32) * 64 + sc];
            pV0 = *(const uint4*)&Vt[((size_t)bh * 64 + sr) * 512 + j0n + sc];
            pV1 = *(const uint4*)&Vt[((size_t)bh * 64 + sr + 32) * 512 + j0n + sc];
            int n0_ = nbase + sr;       if (n0_ > NPOS - 1) n0_ = NPOS - 1;
            int n1_ = nbase + sr + 32;  if (n1_ > NPOS - 1) n1_ = NPOS - 1;
            int n2_ = nbase + sr + 64;  if (n2_ > NPOS - 1) n2_ = NPOS - 1;
            int n3_ = nbase + sr + 96;  if (n3_ > NPOS - 1) n3_ = NPOS - 1;
            pP0 = *(const uint4*)&Ph[((size_t)bh * NPOS + n0_) * 64 + sc];
            pP1 = *(const uint4*)&Ph[((size_t)bh * NPOS + n1_) * 64 + sc];
            pP2 = *(const uint4*)&Ph[((size_t)bh * NPOS + n2_) * 64 + sc];
            pP3 = *(const uint4*)&Ph[((size_t)bh * NPOS + n3_) * 64 + sc];
            const uint4 cm = *(const uint4*)&cmask[(size_t)(i0 + mr) * 512 + j0n + mc];
            const uint4 bm = *(const uint4*)&bmask[(size_t)b * 512 + j0n + mc];
            pM.x = cm.x | bm.x; pM.y = cm.y | bm.y; pM.z = cm.z | bm.z; pM.w = cm.w | bm.w;
        }

        f16x8 afQ[2], afV[2];
        #pragma unroll
        for (int ks = 0; ks < 2; ++ks) {
            afQ[ks] = *(const f16x8*)&Qa[(w * 16 + l15) * 72 + ks * 32 + quad * 8];
            afV[ks] = afQ[ks] + dpbf[ks];
        }
        // AC: 4 blocks x 2 ks
        f32x4 accAC[4];
        #pragma unroll
        for (int nt = 0; nt < 4; ++nt) {
            accAC[nt] = (f32x4){0.f, 0.f, 0.f, 0.f};
            #pragma unroll
            for (int ks = 0; ks < 2; ++ks) {
                const f16x8 bf = *(const f16x8*)&Ka[(nt * 16 + l15) * 72 + ks * 32 + quad * 8];
                accAC[nt] = __builtin_amdgcn_mfma_f32_16x16x32_f16(afQ[ks], bf, accAC[nt], 0, 0, 0);
            }
        }
        // BD: wave-private 79-wide window -> 5 blocks (nw blocks 3-w .. 7-w)
        f32x4 accBD[5];
        #pragma unroll
        for (int u = 0; u < 5; ++u) {
            accBD[u] = (f32x4){0.f, 0.f, 0.f, 0.f};
            const int nts = (3 - w) + u;
            #pragma unroll
            for (int ks = 0; ks < 2; ++ks) {
                const f16x8 bf = *(const f16x8*)&Pa[(nts * 16 + l15) * 72 + ks * 32 + quad * 8];
                accBD[u] = __builtin_amdgcn_mfma_f32_16x16x32_f16(afV[ks], bf, accBD[u], 0, 0, 0);
            }
        }
        __syncthreads();                              // C: Ka/Pa frag reads done (W overwrites Ka)

        // gather (quad-local push permute) + mask + online softmax; W -> Ka wave-own rows
        #pragma unroll
        for (int rg = 0; rg < 4; ++rg) {
            const int qr = quad * 4 + rg;             // quad-local row 0..15
            const int rt = rowt + rg;                 // tile-local row
            float tmpv[5];
            #pragma unroll
            for (int u = 0; u < 5; ++u) {
                const int cl = l15 + (3 + u) * 16 + qr - 63;
                const int dst = (quad * 16 + (cl & 15)) << 2;
                tmpv[u] = __uint_as_float(
                    (unsigned)__builtin_amdgcn_ds_permute(dst, (int)__float_as_uint(accBD[u][rg])));
            }
            const bool hi = l15 > qr;                 // u = nt + (l15 > qr)
            float sv[4]; unsigned mk = 0;
            #pragma unroll
            for (int nt = 0; nt < 4; ++nt) {
                const int c = nt * 16 + l15;
                const float bdv = hi ? tmpv[nt + 1] : tmpv[nt];
                float s = (accAC[nt][rg] + bdv) * 0.125f;
                if (Ma[rt * 64 + c]) { s = -3.402823466e38f; mk |= 1u << nt; }
                sv[nt] = s;
            }
            float tmax = fmaxf(fmaxf(sv[0], sv[1]), fmaxf(sv[2], sv[3]));
            #pragma unroll
            for (int d = 1; d < 16; d <<= 1) tmax = fmaxf(tmax, __shfl_xor(tmax, d));
            const float mnew = fmaxf(m_run[rg], tmax);
            const float alpha = __expf(m_run[rg] - mnew);
            float rsum = 0.f;
            f16 wv[4];
            #pragma unroll
            for (int nt = 0; nt < 4; ++nt) {
                const float e = __expf(sv[nt] - mnew);
                rsum += e;                                      // denom over all j (ref semantics)
                wv[nt] = ((mk >> nt) & 1u) ? (f16)0.f : (f16)e; // zero masked for PV
            }
            #pragma unroll
            for (int d = 1; d < 16; d <<= 1) rsum += __shfl_xor(rsum, d);
            l_run[rg] = l_run[rg] * alpha + rsum;
            m_run[rg] = mnew;
            #pragma unroll
            for (int dt = 0; dt < 4; ++dt) accO[dt][rg] *= alpha;
            #pragma unroll
            for (int nt = 0; nt < 4; ++nt)
                Ka[rt * 72 + nt * 16 + l15] = wv[nt];
        }
        // PV: afW reads wave-own Ka rows (same-wave write -> lgkmcnt, no barrier)
        f16x8 afW[2];
        #pragma unroll
        for (int ks = 0; ks < 2; ++ks)
            afW[ks] = *(const f16x8*)&Ka[(w * 16 + l15) * 72 + ks * 32 + quad * 8];
        #pragma unroll
        for (int dt = 0; dt < 4; ++dt)
            #pragma unroll
            for (int ks = 0; ks < 2; ++ks) {
                const f16x8 bf = *(const f16x8*)&Va[(dt * 16 + l15) * 72 + ks * 32 + quad * 8];
                accO[dt] = __builtin_amdgcn_mfma_f32_16x16x32_f16(afW[ks], bf, accO[dt], 0, 0, 0);
            }
    }

    #pragma unroll
    for (int rg = 0; rg < 4; ++rg) {
        const float inv = 1.0f / l_run[rg];
        const int gi = i0 + rowt + rg;
        #pragma unroll
        for (int dt = 0; dt < 4; ++dt)
            CTX[((size_t)b * 512 + gi) * 512 + h * 64 + dt * 16 + l15] = (f16)(accO[dt][rg] * inv);
    }
}

extern "C" void kernel_launch(void* const* d_in, const int* in_sizes, int n_in,
                              void* d_out, int out_size, void* d_ws, size_t ws_size,
                              hipStream_t stream) {
    const float* query   = (const float*)d_in[0];
    const float* key     = (const float*)d_in[1];
    const float* value   = (const float*)d_in[2];
    const float* pos_enc = (const float*)d_in[3];
    const unsigned char* mask       = (const unsigned char*)d_in[4];
    const unsigned char* chunk_mask = (const unsigned char*)d_in[5];
    const float* Wq  = (const float*)d_in[6];
    const float* bq  = (const float*)d_in[7];
    const float* Wk  = (const float*)d_in[8];
    const float* bk  = (const float*)d_in[9];
    const float* Wv  = (const float*)d_in[10];
    const float* bv  = (const float*)d_in[11];
    const float* Wpos = (const float*)d_in[12];
    const float* Wo   = (const float*)d_in[13];
    const float* bo   = (const float*)d_in[14];
    const float* pbu  = (const float*)d_in[15];
    const float* pbv  = (const float*)d_in[16];
    float* out = (float*)d_out;

    f16* base = (f16*)d_ws;
    size_t off = 0;
    f16* ctx = base + off; off += 4194304;   // (B,T1,E) attn output
    f16* Qhm = base + off; off += 4194304;   // (B,H,T1,DK)  q+bq+pbu
    f16* Khm = base + off; off += 4194304;   // (B,H,T2,DK)
    f16* Vtm = base + off; off += 4194304;   // (B,H,DK,T2)
    f16* Phm = base + off; off += 8380416;   // (B,H,NPOS,DK)

    PArgs pa;
    pa.g[0] = PArg{query,   Wq,   bq, pbu,     (void*)Qhm, 8192,  2, 0};
    pa.g[1] = PArg{key,     Wk,   bk, nullptr, (void*)Khm, 8192,  2, 0};
    pa.g[2] = PArg{value,   Wv,   bv, nullptr, (void*)Vtm, 8192,  1, 0};
    pa.g[3] = PArg{pos_enc, Wpos, nullptr, nullptr, (void*)Phm, 16368, 3, 0};
    proj_all<<<dim3(5120), 256, 0, stream>>>(pa);

    attn_mfma<<<dim3(8, 8, 16), 256, 0, stream>>>(Qhm, Khm, Vtm, Phm, pbu, pbv,
                                                  mask, chunk_mask, ctx);

    PArg go = PArg{ctx, Wo, bo, nullptr, (void*)out, 8192, 0, 1};
    proj_one<<<dim3(1024), 256, 0, stream>>>(go);
}